// Round 1
// baseline (129.716 us; speedup 1.0000x reference)
//
#include <hip/hip_runtime.h>

#define THREADS 256
#define TQ 8          // query points per thread (independent min chains)
#define SPLITM 16     // ref-dimension split for occupancy
#define NPART 256     // partial sums for deterministic reduction

// Pack ref points as {p0, p1, p2, |p|^2} so the inner loop is pure FMA.
__global__ __launch_bounds__(THREADS) void chamfer_pack(
    const float* __restrict__ a, int na,
    const float* __restrict__ bpts, int nb,
    float4* __restrict__ outA, float4* __restrict__ outB)
{
    int total = na + nb;
    for (int i = blockIdx.x * THREADS + threadIdx.x; i < total;
         i += gridDim.x * THREADS) {
        const float* src;
        float4* dst;
        if (i < na) { src = a + (size_t)i * 3;            dst = outA + i; }
        else        { int j = i - na; src = bpts + (size_t)j * 3; dst = outB + j; }
        float x = src[0], y = src[1], z = src[2];
        *dst = make_float4(x, y, z, fmaf(x, x, fmaf(y, y, z * z)));
    }
}

// One launch handles both directions: blockIdx.z = 2*b + dir.
// dir 0: queries = y_true (A), refs = y_pred (B)  -> minA
// dir 1: queries = y_pred (B), refs = y_true (A)  -> minB
// Inner loop per pair: t = fma(-2x2,y2, fma(-2x1,y1, fma(-2x0,y0, |y|^2)));
// min. |x|^2 and clamp applied in epilogue (commute with min).
__global__ __launch_bounds__(THREADS) void chamfer_nn(
    const float* __restrict__ ptsA, const float* __restrict__ ptsB,
    const float4* __restrict__ pkA, const float4* __restrict__ pkB,
    unsigned int* __restrict__ minA, unsigned int* __restrict__ minB,
    int NA, int NB)
{
    int dir = blockIdx.z & 1;
    int b   = blockIdx.z >> 1;
    const float*  qpts  = dir ? ptsB : ptsA;
    const float4* rpk   = dir ? pkA  : pkB;
    unsigned int* minbf = dir ? minB : minA;
    int Nq = dir ? NB : NA;
    int Nr = dir ? NA : NB;

    int qbase = blockIdx.x * (THREADS * TQ) + threadIdx.x;

    float qx[TQ], qy[TQ], qz[TQ], q2[TQ], mv[TQ];
#pragma unroll
    for (int k = 0; k < TQ; ++k) {
        int qi = qbase + k * THREADS;
        float x = 0.f, y = 0.f, z = 0.f;
        if (qi < Nq) {
            const float* p = qpts + ((size_t)b * Nq + qi) * 3;
            x = p[0]; y = p[1]; z = p[2];
        }
        q2[k] = fmaf(x, x, fmaf(y, y, z * z));
        qx[k] = -2.f * x;
        qy[k] = -2.f * y;
        qz[k] = -2.f * z;
        mv[k] = 3.0e38f;
    }

    int nchunk = (Nr + SPLITM - 1) / SPLITM;
    int m0 = blockIdx.y * nchunk;
    int m1 = min(m0 + nchunk, Nr);
    const float4* rp = rpk + (size_t)b * Nr;

#pragma unroll 4
    for (int m = m0; m < m1; ++m) {
        float4 Y = rp[m];   // uniform address -> scalar load expected
#pragma unroll
        for (int k = 0; k < TQ; ++k) {
            float t = fmaf(qz[k], Y.z, Y.w);
            t = fmaf(qy[k], Y.y, t);
            t = fmaf(qx[k], Y.x, t);
            mv[k] = fminf(mv[k], t);
        }
    }

#pragma unroll
    for (int k = 0; k < TQ; ++k) {
        int qi = qbase + k * THREADS;
        if (qi < Nq) {
            float d2 = fmaxf(0.f, q2[k] + mv[k]);  // d2 >= 0 -> uint order == float order
            atomicMin(minbf + (size_t)b * Nq + qi, __float_as_uint(d2));
        }
    }
}

__global__ __launch_bounds__(THREADS) void chamfer_reduce1(
    const unsigned int* __restrict__ vals, int n, float* __restrict__ partial)
{
    __shared__ float sd[THREADS / 64];
    float s = 0.f;
    for (int i = blockIdx.x * THREADS + threadIdx.x; i < n;
         i += gridDim.x * THREADS)
        s += __uint_as_float(vals[i]);
#pragma unroll
    for (int off = 32; off > 0; off >>= 1) s += __shfl_down(s, off, 64);
    int lane = threadIdx.x & 63, w = threadIdx.x >> 6;
    if (lane == 0) sd[w] = s;
    __syncthreads();
    if (threadIdx.x == 0) {
        float t = 0.f;
#pragma unroll
        for (int i = 0; i < THREADS / 64; ++i) t += sd[i];
        partial[blockIdx.x] = t;
    }
}

__global__ __launch_bounds__(THREADS) void chamfer_reduce2(
    const float* __restrict__ partial, int n, float invB, float* __restrict__ out)
{
    __shared__ float sd[THREADS / 64];
    float s = 0.f;
    for (int i = threadIdx.x; i < n; i += THREADS) s += partial[i];
#pragma unroll
    for (int off = 32; off > 0; off >>= 1) s += __shfl_down(s, off, 64);
    int lane = threadIdx.x & 63, w = threadIdx.x >> 6;
    if (lane == 0) sd[w] = s;
    __syncthreads();
    if (threadIdx.x == 0) {
        float t = 0.f;
        for (int i = 0; i < THREADS / 64; ++i) t += sd[i];
        out[0] = t * invB;
    }
}

extern "C" void kernel_launch(void* const* d_in, const int* in_sizes, int n_in,
                              void* d_out, int out_size, void* d_ws, size_t ws_size,
                              hipStream_t stream)
{
    const float* ytrue = (const float*)d_in[0];
    const float* ypred = (const float*)d_in[1];
    const int B = 8, D = 3;
    int NA = in_sizes[0] / (B * D);   // 8192
    int NB = in_sizes[1] / (B * D);   // 8192
    size_t nA = (size_t)B * NA;
    size_t nB = (size_t)B * NB;

    char* ws = (char*)d_ws;
    float4* pkA = (float4*)ws;              ws += nA * sizeof(float4);
    float4* pkB = (float4*)ws;              ws += nB * sizeof(float4);
    unsigned int* minA = (unsigned int*)ws; ws += nA * sizeof(unsigned int);
    unsigned int* minB = (unsigned int*)ws; ws += nB * sizeof(unsigned int);  // adjacent to minA
    float* partial = (float*)ws;            ws += NPART * sizeof(float);

    // Init both min buffers to large positive float (0x7F7F7F7F ~ 3.39e38).
    hipMemsetAsync(minA, 0x7F, (nA + nB) * sizeof(unsigned int), stream);

    int totalPts = (int)(nA + nB);
    int packBlocks = (totalPts + THREADS - 1) / THREADS;
    chamfer_pack<<<packBlocks, THREADS, 0, stream>>>(ytrue, (int)nA, ypred, (int)nB,
                                                     pkA, pkB);

    int maxN = NA > NB ? NA : NB;
    int qblocks = (maxN + THREADS * TQ - 1) / (THREADS * TQ);
    dim3 grid(qblocks, SPLITM, 2 * B);
    chamfer_nn<<<grid, THREADS, 0, stream>>>(ytrue, ypred, pkA, pkB, minA, minB,
                                             NA, NB);

    chamfer_reduce1<<<NPART, THREADS, 0, stream>>>(minA, totalPts, partial);
    chamfer_reduce2<<<1, THREADS, 0, stream>>>(partial, NPART, 1.0f / B,
                                               (float*)d_out);
}